// Round 1
// baseline (552.981 us; speedup 1.0000x reference)
//
#include <hip/hip_runtime.h>
#include <hip/hip_bf16.h>

typedef unsigned short u16;

#define NN_PTS 8192
#define SS_PTS 2048
#define MROWS  65536

// workspace byte offsets (all 16B-aligned)
#define OFF_IDX   0ULL         // int  [65536*3]          786432 B
#define OFF_W     786432ULL    // f32  [65536*3]          786432 B
#define OFF_WT1   1572864ULL   // f32  [320][256]         327680 B
#define OFF_WT2   1900544ULL   // f32  [256][128]         131072 B
#define OFF_ST1   2031616ULL   // f32  [512]  scale/shift   2048 B
#define OFF_ST2   2033664ULL   // f32  [256]  scale/shift   1024 B
#define OFF_P1    2034688ULL   // f32  [1024][512]       2097152 B
#define OFF_P2    4131840ULL   // f32  [1024][256]       1048576 B
#define OFF_H1    5180416ULL   // bf16 [65536][256]     33554432 B
#define OFF_H2    38734848ULL  // bf16 [65536][128]     16777216 B
// total ~55.5 MB

__device__ __forceinline__ u16 f2bf(float x) {
    union { __hip_bfloat16 h; u16 u; } cv;
    cv.h = __float2bfloat16(x);
    return cv.u;
}
__device__ __forceinline__ float bf2f(u16 u) {
    union { unsigned int i; float f; } cv;
    cv.i = ((unsigned int)u) << 16;
    return cv.f;
}

// ---------------------------------------------------------------- transpose
// dst[C][R] = src[R][C]
__global__ __launch_bounds__(256) void transpose_kernel(
    const float* __restrict__ src, float* __restrict__ dst, int R, int C) {
    int o = blockIdx.x * 256 + threadIdx.x;
    if (o < R * C) {
        int rr = o % R;
        int cc = o / R;
        dst[o] = src[rr * C + cc];
    }
}

// ---------------------------------------------------------------- 3-NN + weights
// one thread per query point; whole xyz2 batch slice in LDS as float4(x,y,z,|p|^2)
__global__ __launch_bounds__(256) void knn_kernel(
    const float* __restrict__ xyz1, const float* __restrict__ xyz2,
    int* __restrict__ idxb, float* __restrict__ wb) {
    __shared__ float4 pts[SS_PTS];  // 32 KB
    int t = threadIdx.x;
    int g = blockIdx.x * 256 + t;       // global query row
    int b = g >> 13;                    // g / 8192
    for (int i = t; i < SS_PTS; i += 256) {
        float x = xyz2[((size_t)b * SS_PTS + i) * 3 + 0];
        float y = xyz2[((size_t)b * SS_PTS + i) * 3 + 1];
        float z = xyz2[((size_t)b * SS_PTS + i) * 3 + 2];
        pts[i] = make_float4(x, y, z, x * x + y * y + z * z);
    }
    __syncthreads();

    float qx = xyz1[(size_t)g * 3 + 0];
    float qy = xyz1[(size_t)g * 3 + 1];
    float qz = xyz1[(size_t)g * 3 + 2];
    float m2x = -2.0f * qx, m2y = -2.0f * qy, m2z = -2.0f * qz;
    float qq = qx * qx + qy * qy + qz * qz;

    float d0 = 3.4e38f, d1 = 3.4e38f, d2 = 3.4e38f;
    int j0 = 0, j1 = 0, j2 = 0;
    #pragma unroll 4
    for (int s = 0; s < SS_PTS; ++s) {
        float4 p = pts[s];
        float sc = fmaf(m2x, p.x, fmaf(m2y, p.y, fmaf(m2z, p.z, p.w)));
        if (sc < d2) {
            d2 = sc; j2 = s;
            if (d2 < d1) {
                float td = d1; d1 = d2; d2 = td;
                int tj = j1; j1 = j2; j2 = tj;
                if (d1 < d0) {
                    td = d0; d0 = d1; d1 = td;
                    tj = j0; j0 = j1; j1 = tj;
                }
            }
        }
    }
    // reference: dists = max(qq - 2qp + pp, 1e-10); w = 1/d; w /= sum
    float dd0 = fmaxf(d0 + qq, 1e-10f);
    float dd1 = fmaxf(d1 + qq, 1e-10f);
    float dd2 = fmaxf(d2 + qq, 1e-10f);
    float w0 = 1.0f / dd0, w1 = 1.0f / dd1, w2 = 1.0f / dd2;
    float inv = 1.0f / (w0 + w1 + w2);
    idxb[(size_t)g * 3 + 0] = j0;
    idxb[(size_t)g * 3 + 1] = j1;
    idxb[(size_t)g * 3 + 2] = j2;
    wb[(size_t)g * 3 + 0] = w0 * inv;
    wb[(size_t)g * 3 + 1] = w1 * inv;
    wb[(size_t)g * 3 + 2] = w2 * inv;
}

// ---------------------------------------------------------------- GEMM1 (fused gather)
// h1[g][c] = sum_k A[g][k] * W1[c][k],  A = [points1 (64) | interp (256)]
// block: 64 rows x 256 cols, 256 threads, thread = 8x8
__global__ __launch_bounds__(256) void gemm1_kernel(
    const float* __restrict__ points1, const float* __restrict__ points2,
    const int* __restrict__ idxb, const float* __restrict__ wb,
    const float* __restrict__ wt1,   // [320][256]
    u16* __restrict__ h1, float* __restrict__ part1) {
    __shared__ __align__(16) float As[32][68];    // [k][row]
    __shared__ __align__(16) float Ws[32][256];   // [k][col]
    __shared__ int   idxs[64 * 3];
    __shared__ float wls[64 * 3];
    __shared__ float bsum[256];
    __shared__ float bsq[256];

    int t = threadIdx.x;
    int R0 = blockIdx.x * 64;
    if (t < 192) {
        idxs[t] = idxb[(size_t)R0 * 3 + t];
        wls[t]  = wb[(size_t)R0 * 3 + t];
    }
    bsum[t] = 0.0f;
    bsq[t]  = 0.0f;

    int tx = t & 31;        // col group: cols tx*8..+8
    int ty = t >> 5;        // row group: rows ty*8..+8
    int r  = t >> 2;        // staging row 0..63
    int c0 = (t & 3) * 8;   // staging k-offset {0,8,16,24}

    float acc[8][8];
    #pragma unroll
    for (int i = 0; i < 8; ++i)
        #pragma unroll
        for (int j = 0; j < 8; ++j) acc[i][j] = 0.0f;

    __syncthreads();

    for (int kb = 0; kb < 320; kb += 32) {
        // ---- stage A tile
        if (kb < 64) {
            const float* src = points1 + (size_t)(R0 + r) * 64 + kb + c0;
            float4 v0 = *(const float4*)src;
            float4 v1 = *(const float4*)(src + 4);
            As[c0 + 0][r] = v0.x; As[c0 + 1][r] = v0.y;
            As[c0 + 2][r] = v0.z; As[c0 + 3][r] = v0.w;
            As[c0 + 4][r] = v1.x; As[c0 + 5][r] = v1.y;
            As[c0 + 6][r] = v1.z; As[c0 + 7][r] = v1.w;
        } else {
            int b = (R0 + r) >> 13;
            int i0 = idxs[r * 3 + 0], i1 = idxs[r * 3 + 1], i2 = idxs[r * 3 + 2];
            float w0 = wls[r * 3 + 0], w1 = wls[r * 3 + 1], w2 = wls[r * 3 + 2];
            size_t base = (size_t)b * SS_PTS;
            int joff = kb - 64 + c0;
            const float* p0 = points2 + (base + i0) * 256 + joff;
            const float* p1 = points2 + (base + i1) * 256 + joff;
            const float* p2 = points2 + (base + i2) * 256 + joff;
            float4 a0 = ((const float4*)p0)[0], a1 = ((const float4*)p0)[1];
            float4 b0 = ((const float4*)p1)[0], b1 = ((const float4*)p1)[1];
            float4 cc0 = ((const float4*)p2)[0], cc1 = ((const float4*)p2)[1];
            float av[8] = {a0.x, a0.y, a0.z, a0.w, a1.x, a1.y, a1.z, a1.w};
            float bv[8] = {b0.x, b0.y, b0.z, b0.w, b1.x, b1.y, b1.z, b1.w};
            float cv[8] = {cc0.x, cc0.y, cc0.z, cc0.w, cc1.x, cc1.y, cc1.z, cc1.w};
            #pragma unroll
            for (int j = 0; j < 8; ++j)
                As[c0 + j][r] = fmaf(w0, av[j], fmaf(w1, bv[j], w2 * cv[j]));
        }
        // ---- stage W tile: Ws[k][o] = wt1[(kb+k)*256 + o], o = t
        {
            const float* wsrc = wt1 + (size_t)kb * 256 + t;
            #pragma unroll
            for (int k = 0; k < 32; ++k) Ws[k][t] = wsrc[(size_t)k * 256];
        }
        __syncthreads();

        #pragma unroll 8
        for (int k = 0; k < 32; ++k) {
            float4 a0 = *(const float4*)&As[k][ty * 8];
            float4 a1 = *(const float4*)&As[k][ty * 8 + 4];
            float4 b0 = *(const float4*)&Ws[k][tx * 8];
            float4 b1 = *(const float4*)&Ws[k][tx * 8 + 4];
            float av[8] = {a0.x, a0.y, a0.z, a0.w, a1.x, a1.y, a1.z, a1.w};
            float bv[8] = {b0.x, b0.y, b0.z, b0.w, b1.x, b1.y, b1.z, b1.w};
            #pragma unroll
            for (int i = 0; i < 8; ++i)
                #pragma unroll
                for (int j = 0; j < 8; ++j)
                    acc[i][j] = fmaf(av[i], bv[j], acc[i][j]);
        }
        __syncthreads();
    }

    // ---- epilogue: store h1 (bf16, raw pre-BN) + per-block channel stats
    #pragma unroll
    for (int i = 0; i < 8; ++i) {
        union { u16 u[8]; float4 f; } pk;
        #pragma unroll
        for (int j = 0; j < 8; ++j) pk.u[j] = f2bf(acc[i][j]);
        *(float4*)(h1 + (size_t)(R0 + ty * 8 + i) * 256 + tx * 8) = pk.f;
    }
    #pragma unroll
    for (int j = 0; j < 8; ++j) {
        float s = 0.0f, q = 0.0f;
        #pragma unroll
        for (int i = 0; i < 8; ++i) {
            s += acc[i][j];
            q = fmaf(acc[i][j], acc[i][j], q);
        }
        atomicAdd(&bsum[tx * 8 + j], s);
        atomicAdd(&bsq[tx * 8 + j], q);
    }
    __syncthreads();
    part1[(size_t)blockIdx.x * 512 + t * 2 + 0] = bsum[t];
    part1[(size_t)blockIdx.x * 512 + t * 2 + 1] = bsq[t];
}

// ---------------------------------------------------------------- stats reduce
// part layout: [nblk][2C] with channel c at (2c, 2c+1) = (sum, sumsq)
// st output: [0..C) scale, [C..2C) shift. grid = C/16 blocks.
__global__ __launch_bounds__(256) void reduce_kernel(
    const float* __restrict__ part, int nblk, int C, float invM,
    const float* __restrict__ gam, const float* __restrict__ bet,
    float* __restrict__ st) {
    __shared__ float red[256];
    int t = threadIdx.x;
    int slot = t & 31, ig = t >> 5;
    int cb = blockIdx.x * 16;
    float p = 0.0f;
    for (int i = ig; i < nblk; i += 8)
        p += part[(size_t)i * (2 * C) + cb * 2 + slot];
    red[t] = p;
    __syncthreads();
    if (t < 32) {
        float tot = red[t];
        #pragma unroll
        for (int k = 1; k < 8; ++k) tot += red[k * 32 + t];
        red[t] = tot;
    }
    __syncthreads();
    if (t < 16) {
        int c = cb + t;
        float sum = red[2 * t], sq = red[2 * t + 1];
        float mean = sum * invM;
        float var  = sq * invM - mean * mean;
        float rs   = rsqrtf(var + 1e-5f);
        float scv  = gam[c] * rs;
        st[c]     = scv;
        st[C + c] = bet[c] - mean * scv;
    }
}

// ---------------------------------------------------------------- GEMM2
// A = relu(bn1(h1)) computed during staging; h2 raw pre-BN2 out, + stats
__global__ __launch_bounds__(256) void gemm2_kernel(
    const u16* __restrict__ h1, const float* __restrict__ wt2,  // [256][128]
    const float* __restrict__ st1,
    u16* __restrict__ h2, float* __restrict__ part2) {
    __shared__ __align__(16) float As[32][68];
    __shared__ __align__(16) float Ws[32][128];
    __shared__ float sc1[256], sh1[256];
    __shared__ float bsum[128], bsq[128];

    int t = threadIdx.x;
    int R0 = blockIdx.x * 64;
    sc1[t] = st1[t];
    sh1[t] = st1[256 + t];
    if (t < 128) { bsum[t] = 0.0f; bsq[t] = 0.0f; }

    int tx = t & 31;        // cols tx*4..+4
    int ty = t >> 5;        // rows ty*8..+8
    int r  = t >> 2;
    int c0 = (t & 3) * 8;

    float acc[8][4];
    #pragma unroll
    for (int i = 0; i < 8; ++i)
        #pragma unroll
        for (int j = 0; j < 4; ++j) acc[i][j] = 0.0f;

    __syncthreads();

    for (int kb = 0; kb < 256; kb += 32) {
        // ---- stage A: bf16 load + BN1 + relu
        {
            const u16* hp = h1 + (size_t)(R0 + r) * 256 + kb + c0;
            union { float4 f; u16 u[8]; } ld;
            ld.f = *(const float4*)hp;
            #pragma unroll
            for (int j = 0; j < 8; ++j) {
                int ch = kb + c0 + j;
                float v = fmaf(bf2f(ld.u[j]), sc1[ch], sh1[ch]);
                As[c0 + j][r] = fmaxf(v, 0.0f);
            }
        }
        // ---- stage W: thread t -> k = t/8, o0 = (t%8)*16
        {
            int k  = t >> 3;
            int o0 = (t & 7) * 16;
            const float* wsrc = wt2 + (size_t)(kb + k) * 128 + o0;
            float4 w0 = ((const float4*)wsrc)[0];
            float4 w1 = ((const float4*)wsrc)[1];
            float4 w2 = ((const float4*)wsrc)[2];
            float4 w3 = ((const float4*)wsrc)[3];
            ((float4*)&Ws[k][o0])[0] = w0;
            ((float4*)&Ws[k][o0])[1] = w1;
            ((float4*)&Ws[k][o0])[2] = w2;
            ((float4*)&Ws[k][o0])[3] = w3;
        }
        __syncthreads();

        #pragma unroll 8
        for (int k = 0; k < 32; ++k) {
            float4 a0 = *(const float4*)&As[k][ty * 8];
            float4 a1 = *(const float4*)&As[k][ty * 8 + 4];
            float4 b0 = *(const float4*)&Ws[k][tx * 4];
            float av[8] = {a0.x, a0.y, a0.z, a0.w, a1.x, a1.y, a1.z, a1.w};
            float bv[4] = {b0.x, b0.y, b0.z, b0.w};
            #pragma unroll
            for (int i = 0; i < 8; ++i)
                #pragma unroll
                for (int j = 0; j < 4; ++j)
                    acc[i][j] = fmaf(av[i], bv[j], acc[i][j]);
        }
        __syncthreads();
    }

    #pragma unroll
    for (int i = 0; i < 8; ++i) {
        union { u16 u[4]; float2 f; } pk;
        #pragma unroll
        for (int j = 0; j < 4; ++j) pk.u[j] = f2bf(acc[i][j]);
        *(float2*)(h2 + (size_t)(R0 + ty * 8 + i) * 128 + tx * 4) = pk.f;
    }
    #pragma unroll
    for (int j = 0; j < 4; ++j) {
        float s = 0.0f, q = 0.0f;
        #pragma unroll
        for (int i = 0; i < 8; ++i) {
            s += acc[i][j];
            q = fmaf(acc[i][j], acc[i][j], q);
        }
        atomicAdd(&bsum[tx * 4 + j], s);
        atomicAdd(&bsq[tx * 4 + j], q);
    }
    __syncthreads();
    if (t < 128) {
        part2[(size_t)blockIdx.x * 256 + t * 2 + 0] = bsum[t];
        part2[(size_t)blockIdx.x * 256 + t * 2 + 1] = bsq[t];
    }
}

// ---------------------------------------------------------------- final BN2 + relu
__global__ __launch_bounds__(256) void final_kernel(
    const u16* __restrict__ h2, const float* __restrict__ st2,
    float* __restrict__ out) {
    __shared__ float l[256];
    int t = threadIdx.x;
    l[t] = st2[t];
    __syncthreads();
    size_t e0 = ((size_t)blockIdx.x * 256 + t) * 8;
    int c0 = (int)(e0 & 127);
    union { float4 f; u16 u[8]; } ld;
    ld.f = *(const float4*)(h2 + e0);
    float o[8];
    #pragma unroll
    for (int j = 0; j < 8; ++j) {
        int c = c0 + j;
        float v = fmaf(bf2f(ld.u[j]), l[c], l[128 + c]);
        o[j] = fmaxf(v, 0.0f);
    }
    float4* op = (float4*)(out + e0);
    float4 r0; r0.x = o[0]; r0.y = o[1]; r0.z = o[2]; r0.w = o[3];
    float4 r1; r1.x = o[4]; r1.y = o[5]; r1.z = o[6]; r1.w = o[7];
    op[0] = r0;
    op[1] = r1;
}

// ----------------------------------------------------------------
extern "C" void kernel_launch(void* const* d_in, const int* in_sizes, int n_in,
                              void* d_out, int out_size, void* d_ws, size_t ws_size,
                              hipStream_t stream) {
    (void)in_sizes; (void)n_in; (void)out_size; (void)ws_size;
    const float* xyz1    = (const float*)d_in[0];
    const float* xyz2    = (const float*)d_in[1];
    const float* points1 = (const float*)d_in[2];
    const float* points2 = (const float*)d_in[3];
    const float* W1      = (const float*)d_in[4];
    const float* g1      = (const float*)d_in[5];
    const float* b1      = (const float*)d_in[6];
    const float* W2      = (const float*)d_in[7];
    const float* g2      = (const float*)d_in[8];
    const float* b2      = (const float*)d_in[9];

    char* ws = (char*)d_ws;
    int*   idxb = (int*)(ws + OFF_IDX);
    float* wb   = (float*)(ws + OFF_W);
    float* wt1  = (float*)(ws + OFF_WT1);
    float* wt2  = (float*)(ws + OFF_WT2);
    float* st1  = (float*)(ws + OFF_ST1);
    float* st2  = (float*)(ws + OFF_ST2);
    float* p1   = (float*)(ws + OFF_P1);
    float* p2   = (float*)(ws + OFF_P2);
    u16*   h1   = (u16*)(ws + OFF_H1);
    u16*   h2   = (u16*)(ws + OFF_H2);
    float* outp = (float*)d_out;

    transpose_kernel<<<320, 256, 0, stream>>>(W1, wt1, 256, 320);
    transpose_kernel<<<128, 256, 0, stream>>>(W2, wt2, 128, 256);
    knn_kernel<<<256, 256, 0, stream>>>(xyz1, xyz2, idxb, wb);
    gemm1_kernel<<<1024, 256, 0, stream>>>(points1, points2, idxb, wb, wt1, h1, p1);
    reduce_kernel<<<16, 256, 0, stream>>>(p1, 1024, 256, 1.0f / 65536.0f, g1, b1, st1);
    gemm2_kernel<<<1024, 256, 0, stream>>>(h1, wt2, st1, h2, p2);
    reduce_kernel<<<8, 256, 0, stream>>>(p2, 1024, 128, 1.0f / 65536.0f, g2, b2, st2);
    final_kernel<<<4096, 256, 0, stream>>>(h2, st2, outp);
}

// Round 2
// 397.354 us; speedup vs baseline: 1.3917x; 1.3917x over previous
//
#include <hip/hip_runtime.h>
#include <hip/hip_bf16.h>

typedef unsigned short u16;
typedef short bf16x8 __attribute__((ext_vector_type(8)));   // 8 bf16 = 4 VGPRs (per guide)
typedef float f32x4 __attribute__((ext_vector_type(4)));

#define SS_PTS 2048

// workspace byte offsets (all 16B-aligned)
#define OFF_IDX   0ULL         // int  [65536*3]
#define OFF_W     786432ULL    // f32  [65536*3]
#define OFF_WT1B  1572864ULL   // bf16 [256][320]
#define OFF_WT2B  1736704ULL   // bf16 [128][256]
#define OFF_ST1   1802240ULL   // f32  [512]
#define OFF_ST2   1804288ULL   // f32  [256]
#define OFF_P1    1805312ULL   // f32  [1024][512]
#define OFF_P2    3902464ULL   // f32  [512][256]
#define OFF_H1    4426752ULL   // bf16 [65536][256]
#define OFF_H2    37981184ULL  // bf16 [65536][128]
// end 54,758,400 B

__device__ __forceinline__ u16 f2bf(float x) {
    union { __hip_bfloat16 h; u16 u; } cv;
    cv.h = __float2bfloat16(x);
    return cv.u;
}
__device__ __forceinline__ float bf2f(u16 u) {
    union { unsigned int i; float f; } cv;
    cv.i = ((unsigned int)u) << 16;
    return cv.f;
}
__device__ __forceinline__ float4 pack8(const float* v) {
    union { u16 u[8]; float4 f; } pk;
    #pragma unroll
    for (int j = 0; j < 8; ++j) pk.u[j] = f2bf(v[j]);
    return pk.f;
}

// ---------------------------------------------------------------- prep: W -> bf16
__global__ __launch_bounds__(256) void prep_kernel(
    const float* __restrict__ W1, const float* __restrict__ W2,
    u16* __restrict__ wt1b, u16* __restrict__ wt2b) {
    int i = blockIdx.x * 256 + threadIdx.x;
    if (i < 81920) wt1b[i] = f2bf(W1[i]);
    if (i < 32768) wt2b[i] = f2bf(W2[i]);
}

// ---------------------------------------------------------------- 3-NN + weights
// 64 queries/block, 4 threads/query scanning 512 pts each, then merge.
__global__ __launch_bounds__(256) void knn_kernel(
    const float* __restrict__ xyz1, const float* __restrict__ xyz2,
    int* __restrict__ idxb, float* __restrict__ wb) {
    __shared__ float4 pts[2051];          // 4 regions of 513 (bank stagger)
    __shared__ float cd[64][4][3];
    __shared__ int   ci[64][4][3];
    int t = threadIdx.x;
    int bq = blockIdx.x;                  // 0..1023
    int b = bq >> 7;                      // 128 blocks per batch
    const float* x2b = xyz2 + (size_t)b * SS_PTS * 3;
    for (int j = t; j < SS_PTS; j += 256) {
        float x = x2b[j * 3 + 0], y = x2b[j * 3 + 1], z = x2b[j * 3 + 2];
        pts[(j >> 9) * 513 + (j & 511)] = make_float4(x, y, z, x * x + y * y + z * z);
    }
    int lq = t >> 2, p = t & 3;
    int g = bq * 64 + lq;
    float qx = xyz1[(size_t)g * 3 + 0];
    float qy = xyz1[(size_t)g * 3 + 1];
    float qz = xyz1[(size_t)g * 3 + 2];
    __syncthreads();

    float m2x = -2.0f * qx, m2y = -2.0f * qy, m2z = -2.0f * qz;
    float d0 = 3.4e38f, d1 = 3.4e38f, d2 = 3.4e38f;
    int j0 = 0, j1 = 0, j2 = 0;
    int base = p * 513, sbase = p * 512;
    #pragma unroll 4
    for (int s = 0; s < 512; ++s) {
        float4 pt = pts[base + s];
        float sc = fmaf(m2x, pt.x, fmaf(m2y, pt.y, fmaf(m2z, pt.z, pt.w)));
        if (sc < d2) {
            d2 = sc; j2 = sbase + s;
            if (d2 < d1) {
                float td = d1; d1 = d2; d2 = td;
                int tj = j1; j1 = j2; j2 = tj;
                if (d1 < d0) {
                    td = d0; d0 = d1; d1 = td;
                    tj = j0; j0 = j1; j1 = tj;
                }
            }
        }
    }
    cd[lq][p][0] = d0; cd[lq][p][1] = d1; cd[lq][p][2] = d2;
    ci[lq][p][0] = j0; ci[lq][p][1] = j1; ci[lq][p][2] = j2;
    __syncthreads();

    if (p == 0) {
        float e0 = 3.4e38f, e1 = 3.4e38f, e2 = 3.4e38f;
        int k0 = 0, k1 = 0, k2 = 0;
        #pragma unroll
        for (int pp = 0; pp < 4; ++pp)
            #pragma unroll
            for (int e = 0; e < 3; ++e) {
                float sc = cd[lq][pp][e];
                int sj = ci[lq][pp][e];
                if (sc < e2) {
                    e2 = sc; k2 = sj;
                    if (e2 < e1) {
                        float td = e1; e1 = e2; e2 = td;
                        int tj = k1; k1 = k2; k2 = tj;
                        if (e1 < e0) {
                            td = e0; e0 = e1; e1 = td;
                            tj = k0; k0 = k1; k1 = tj;
                        }
                    }
                }
            }
        float qq = qx * qx + qy * qy + qz * qz;
        float dd0 = fmaxf(e0 + qq, 1e-10f);
        float dd1 = fmaxf(e1 + qq, 1e-10f);
        float dd2 = fmaxf(e2 + qq, 1e-10f);
        float w0 = 1.0f / dd0, w1 = 1.0f / dd1, w2 = 1.0f / dd2;
        float inv = 1.0f / (w0 + w1 + w2);
        idxb[(size_t)g * 3 + 0] = k0;
        idxb[(size_t)g * 3 + 1] = k1;
        idxb[(size_t)g * 3 + 2] = k2;
        wb[(size_t)g * 3 + 0] = w0 * inv;
        wb[(size_t)g * 3 + 1] = w1 * inv;
        wb[(size_t)g * 3 + 2] = w2 * inv;
    }
}

// ---------------------------------------------------------------- GEMM1 (MFMA, fused gather)
// C[65536,256] = A[65536,320] x W1^T ; tile 128x128, 4 waves of 64x64.
// LDS tiles: rows of 32 bf16 (64B) with 16B-block XOR swizzle -> conflict-free.
__global__ __launch_bounds__(256) void gemm1_kernel(
    const float* __restrict__ points1, const float* __restrict__ points2,
    const int* __restrict__ idxb, const float* __restrict__ wb,
    const u16* __restrict__ wt1b, u16* __restrict__ h1, float* __restrict__ part1) {
    __shared__ __align__(16) u16 As[128 * 32];
    __shared__ __align__(16) u16 Bs[128 * 32];
    __shared__ int   idxs[384];
    __shared__ float wls[384];
    __shared__ float bsum[128], bsq[128];

    int t = threadIdx.x;
    int bx = blockIdx.x;
    int colt = bx & 1;
    int R0 = (bx >> 1) * 128;
    int C0 = colt * 128;
    int bb = R0 >> 13;

    idxs[t] = idxb[(size_t)R0 * 3 + t];
    wls[t]  = wb[(size_t)R0 * 3 + t];
    if (t < 128) {
        idxs[256 + t] = idxb[(size_t)R0 * 3 + 256 + t];
        wls[256 + t]  = wb[(size_t)R0 * 3 + 256 + t];
        bsum[t] = 0.0f; bsq[t] = 0.0f;
    }

    int m = t >> 1, half = t & 1;
    int sm = (m >> 1) & 3;

    int w = t >> 6, l = t & 63;
    int wr64 = (w >> 1) * 64, wc64 = (w & 1) * 64;
    int l15 = l & 15, q = l >> 4;

    f32x4 acc[4][4];
    #pragma unroll
    for (int i = 0; i < 4; ++i)
        #pragma unroll
        for (int j = 0; j < 4; ++j) acc[i][j] = (f32x4){0.f, 0.f, 0.f, 0.f};

    const float* p2b = points2 + (size_t)bb * SS_PTS * 256;

    for (int kb = 0; kb < 320; kb += 32) {
        // ---- stage A (bf16, swizzled)
        if (kb < 64) {
            const float* src = points1 + (size_t)(R0 + m) * 64 + kb + half * 16;
            float va[16];
            float4 v0 = ((const float4*)src)[0];
            float4 v1 = ((const float4*)src)[1];
            float4 v2 = ((const float4*)src)[2];
            float4 v3 = ((const float4*)src)[3];
            va[0]=v0.x; va[1]=v0.y; va[2]=v0.z; va[3]=v0.w;
            va[4]=v1.x; va[5]=v1.y; va[6]=v1.z; va[7]=v1.w;
            va[8]=v2.x; va[9]=v2.y; va[10]=v2.z; va[11]=v2.w;
            va[12]=v3.x; va[13]=v3.y; va[14]=v3.z; va[15]=v3.w;
            *(float4*)&As[m * 32 + (((half * 2 + 0) ^ sm) << 3)] = pack8(va);
            *(float4*)&As[m * 32 + (((half * 2 + 1) ^ sm) << 3)] = pack8(va + 8);
        } else {
            int i0 = idxs[m * 3 + 0], i1 = idxs[m * 3 + 1], i2 = idxs[m * 3 + 2];
            float w0 = wls[m * 3 + 0], w1 = wls[m * 3 + 1], w2 = wls[m * 3 + 2];
            const float* r0p = p2b + (size_t)i0 * 256;
            const float* r1p = p2b + (size_t)i1 * 256;
            const float* r2p = p2b + (size_t)i2 * 256;
            #pragma unroll
            for (int c2 = 0; c2 < 2; ++c2) {
                int jo = kb - 64 + half * 16 + c2 * 8;
                float4 a0 = ((const float4*)(r0p + jo))[0], a1 = ((const float4*)(r0p + jo))[1];
                float4 b0 = ((const float4*)(r1p + jo))[0], b1 = ((const float4*)(r1p + jo))[1];
                float4 c0 = ((const float4*)(r2p + jo))[0], c1 = ((const float4*)(r2p + jo))[1];
                float av[8] = {a0.x,a0.y,a0.z,a0.w,a1.x,a1.y,a1.z,a1.w};
                float bv[8] = {b0.x,b0.y,b0.z,b0.w,b1.x,b1.y,b1.z,b1.w};
                float cv[8] = {c0.x,c0.y,c0.z,c0.w,c1.x,c1.y,c1.z,c1.w};
                float ov[8];
                #pragma unroll
                for (int j = 0; j < 8; ++j)
                    ov[j] = fmaf(w0, av[j], fmaf(w1, bv[j], w2 * cv[j]));
                *(float4*)&As[m * 32 + (((half * 2 + c2) ^ sm) << 3)] = pack8(ov);
            }
        }
        // ---- stage B (bf16 rows of W1: [n][k], k contiguous)
        {
            const u16* wsrc = wt1b + (size_t)(C0 + m) * 320 + kb + half * 16;
            float4 w0 = ((const float4*)wsrc)[0];
            float4 w1 = ((const float4*)wsrc)[1];
            *(float4*)&Bs[m * 32 + (((half * 2 + 0) ^ sm) << 3)] = w0;
            *(float4*)&Bs[m * 32 + (((half * 2 + 1) ^ sm) << 3)] = w1;
        }
        __syncthreads();

        union uf { float4 f; bf16x8 v; };
        uf af[4], bfr[4];
        #pragma unroll
        for (int fi = 0; fi < 4; ++fi) {
            int ml = wr64 + fi * 16 + l15;
            af[fi].f = *(const float4*)&As[ml * 32 + ((q ^ ((ml >> 1) & 3)) << 3)];
        }
        #pragma unroll
        for (int fj = 0; fj < 4; ++fj) {
            int nl = wc64 + fj * 16 + l15;
            bfr[fj].f = *(const float4*)&Bs[nl * 32 + ((q ^ ((nl >> 1) & 3)) << 3)];
        }
        #pragma unroll
        for (int fi = 0; fi < 4; ++fi)
            #pragma unroll
            for (int fj = 0; fj < 4; ++fj)
                acc[fi][fj] = __builtin_amdgcn_mfma_f32_16x16x32_bf16(
                    bfr[fj].v, af[fi].v, acc[fi][fj], 0, 0, 0);
        __syncthreads();
    }

    // ---- epilogue: h1 store (row-major 4-col packs) + channel stats
    #pragma unroll
    for (int fi = 0; fi < 4; ++fi) {
        int rg = R0 + wr64 + fi * 16 + l15;
        #pragma unroll
        for (int fj = 0; fj < 4; ++fj) {
            int cl = wc64 + fj * 16 + q * 4;
            union { u16 u[4]; float2 f; } pk;
            #pragma unroll
            for (int i = 0; i < 4; ++i) pk.u[i] = f2bf(acc[fi][fj][i]);
            *(float2*)&h1[(size_t)rg * 256 + C0 + cl] = pk.f;
        }
    }
    #pragma unroll
    for (int fj = 0; fj < 4; ++fj)
        #pragma unroll
        for (int i = 0; i < 4; ++i) {
            int cl = wc64 + fj * 16 + q * 4 + i;
            float s = acc[0][fj][i] + acc[1][fj][i] + acc[2][fj][i] + acc[3][fj][i];
            float sq = acc[0][fj][i]*acc[0][fj][i] + acc[1][fj][i]*acc[1][fj][i]
                     + acc[2][fj][i]*acc[2][fj][i] + acc[3][fj][i]*acc[3][fj][i];
            atomicAdd(&bsum[cl], s);
            atomicAdd(&bsq[cl], sq);
        }
    __syncthreads();
    bool on = (t >> 7) == colt;
    int lc = t & 127;
    part1[(size_t)bx * 512 + t * 2 + 0] = on ? bsum[lc] : 0.0f;
    part1[(size_t)bx * 512 + t * 2 + 1] = on ? bsq[lc] : 0.0f;
}

// ---------------------------------------------------------------- stats reduce
__global__ __launch_bounds__(256) void reduce_kernel(
    const float* __restrict__ part, int nblk, int C, float invM,
    const float* __restrict__ gam, const float* __restrict__ bet,
    float* __restrict__ st) {
    __shared__ float red[256];
    int t = threadIdx.x;
    int slot = t & 31, ig = t >> 5;
    int cb = blockIdx.x * 16;
    float p = 0.0f;
    for (int i = ig; i < nblk; i += 8)
        p += part[(size_t)i * (2 * C) + cb * 2 + slot];
    red[t] = p;
    __syncthreads();
    if (t < 32) {
        float tot = red[t];
        #pragma unroll
        for (int k = 1; k < 8; ++k) tot += red[k * 32 + t];
        red[t] = tot;
    }
    __syncthreads();
    if (t < 16) {
        int c = cb + t;
        float sum = red[2 * t], sq = red[2 * t + 1];
        float mean = sum * invM;
        float var  = sq * invM - mean * mean;
        float rs   = rsqrtf(var + 1e-5f);
        float scv  = gam[c] * rs;
        st[c]     = scv;
        st[C + c] = bet[c] - mean * scv;
    }
}

// ---------------------------------------------------------------- GEMM2 (MFMA)
// C[65536,128] = relu(bn1(h1))[65536,256] x W2^T ; tile 128x128.
__global__ __launch_bounds__(256) void gemm2_kernel(
    const u16* __restrict__ h1, const u16* __restrict__ wt2b,
    const float* __restrict__ st1,
    u16* __restrict__ h2, float* __restrict__ part2) {
    __shared__ __align__(16) u16 As[128 * 32];
    __shared__ __align__(16) u16 Bs[128 * 32];
    __shared__ float sc1[256], sh1[256];
    __shared__ float bsum[128], bsq[128];

    int t = threadIdx.x;
    int bx = blockIdx.x;
    int R0 = bx * 128;
    sc1[t] = st1[t];
    sh1[t] = st1[256 + t];
    if (t < 128) { bsum[t] = 0.0f; bsq[t] = 0.0f; }

    int m = t >> 1, half = t & 1;
    int sm = (m >> 1) & 3;
    int w = t >> 6, l = t & 63;
    int wr64 = (w >> 1) * 64, wc64 = (w & 1) * 64;
    int l15 = l & 15, q = l >> 4;

    f32x4 acc[4][4];
    #pragma unroll
    for (int i = 0; i < 4; ++i)
        #pragma unroll
        for (int j = 0; j < 4; ++j) acc[i][j] = (f32x4){0.f, 0.f, 0.f, 0.f};

    __syncthreads();

    for (int kb = 0; kb < 256; kb += 32) {
        // ---- stage A: h1 bf16 -> BN1+relu -> bf16 (swizzled)
        {
            const u16* src = h1 + (size_t)(R0 + m) * 256 + kb + half * 16;
            union { float4 f; u16 u[8]; } ld0, ld1;
            ld0.f = ((const float4*)src)[0];
            ld1.f = ((const float4*)src)[1];
            int ch0 = kb + half * 16;
            float o0[8], o1[8];
            #pragma unroll
            for (int j = 0; j < 8; ++j) {
                float v = fmaf(bf2f(ld0.u[j]), sc1[ch0 + j], sh1[ch0 + j]);
                o0[j] = fmaxf(v, 0.0f);
            }
            #pragma unroll
            for (int j = 0; j < 8; ++j) {
                float v = fmaf(bf2f(ld1.u[j]), sc1[ch0 + 8 + j], sh1[ch0 + 8 + j]);
                o1[j] = fmaxf(v, 0.0f);
            }
            *(float4*)&As[m * 32 + (((half * 2 + 0) ^ sm) << 3)] = pack8(o0);
            *(float4*)&As[m * 32 + (((half * 2 + 1) ^ sm) << 3)] = pack8(o1);
        }
        // ---- stage B
        {
            const u16* wsrc = wt2b + (size_t)m * 256 + kb + half * 16;
            float4 w0 = ((const float4*)wsrc)[0];
            float4 w1 = ((const float4*)wsrc)[1];
            *(float4*)&Bs[m * 32 + (((half * 2 + 0) ^ sm) << 3)] = w0;
            *(float4*)&Bs[m * 32 + (((half * 2 + 1) ^ sm) << 3)] = w1;
        }
        __syncthreads();

        union uf { float4 f; bf16x8 v; };
        uf af[4], bfr[4];
        #pragma unroll
        for (int fi = 0; fi < 4; ++fi) {
            int ml = wr64 + fi * 16 + l15;
            af[fi].f = *(const float4*)&As[ml * 32 + ((q ^ ((ml >> 1) & 3)) << 3)];
        }
        #pragma unroll
        for (int fj = 0; fj < 4; ++fj) {
            int nl = wc64 + fj * 16 + l15;
            bfr[fj].f = *(const float4*)&Bs[nl * 32 + ((q ^ ((nl >> 1) & 3)) << 3)];
        }
        #pragma unroll
        for (int fi = 0; fi < 4; ++fi)
            #pragma unroll
            for (int fj = 0; fj < 4; ++fj)
                acc[fi][fj] = __builtin_amdgcn_mfma_f32_16x16x32_bf16(
                    bfr[fj].v, af[fi].v, acc[fi][fj], 0, 0, 0);
        __syncthreads();
    }

    #pragma unroll
    for (int fi = 0; fi < 4; ++fi) {
        int rg = R0 + wr64 + fi * 16 + l15;
        #pragma unroll
        for (int fj = 0; fj < 4; ++fj) {
            int cl = wc64 + fj * 16 + q * 4;
            union { u16 u[4]; float2 f; } pk;
            #pragma unroll
            for (int i = 0; i < 4; ++i) pk.u[i] = f2bf(acc[fi][fj][i]);
            *(float2*)&h2[(size_t)rg * 128 + cl] = pk.f;
        }
    }
    #pragma unroll
    for (int fj = 0; fj < 4; ++fj)
        #pragma unroll
        for (int i = 0; i < 4; ++i) {
            int cl = wc64 + fj * 16 + q * 4 + i;
            float s = acc[0][fj][i] + acc[1][fj][i] + acc[2][fj][i] + acc[3][fj][i];
            float sq = acc[0][fj][i]*acc[0][fj][i] + acc[1][fj][i]*acc[1][fj][i]
                     + acc[2][fj][i]*acc[2][fj][i] + acc[3][fj][i]*acc[3][fj][i];
            atomicAdd(&bsum[cl], s);
            atomicAdd(&bsq[cl], sq);
        }
    __syncthreads();
    if (t < 128) {
        part2[(size_t)bx * 256 + t * 2 + 0] = bsum[t];
        part2[(size_t)bx * 256 + t * 2 + 1] = bsq[t];
    }
}

// ---------------------------------------------------------------- final BN2 + relu
__global__ __launch_bounds__(256) void final_kernel(
    const u16* __restrict__ h2, const float* __restrict__ st2,
    float* __restrict__ out) {
    __shared__ float lst[256];
    int t = threadIdx.x;
    lst[t] = st2[t];
    __syncthreads();
    size_t e0 = ((size_t)blockIdx.x * 256 + t) * 8;
    int c0 = (int)(e0 & 127);
    union { float4 f; u16 u[8]; } ld;
    ld.f = *(const float4*)(h2 + e0);
    float o[8];
    #pragma unroll
    for (int j = 0; j < 8; ++j) {
        int c = c0 + j;
        float v = fmaf(bf2f(ld.u[j]), lst[c], lst[128 + c]);
        o[j] = fmaxf(v, 0.0f);
    }
    float4* op = (float4*)(out + e0);
    float4 r0; r0.x = o[0]; r0.y = o[1]; r0.z = o[2]; r0.w = o[3];
    float4 r1; r1.x = o[4]; r1.y = o[5]; r1.z = o[6]; r1.w = o[7];
    op[0] = r0;
    op[1] = r1;
}

// ----------------------------------------------------------------
extern "C" void kernel_launch(void* const* d_in, const int* in_sizes, int n_in,
                              void* d_out, int out_size, void* d_ws, size_t ws_size,
                              hipStream_t stream) {
    (void)in_sizes; (void)n_in; (void)out_size; (void)ws_size;
    const float* xyz1    = (const float*)d_in[0];
    const float* xyz2    = (const float*)d_in[1];
    const float* points1 = (const float*)d_in[2];
    const float* points2 = (const float*)d_in[3];
    const float* W1      = (const float*)d_in[4];
    const float* g1      = (const float*)d_in[5];
    const float* b1      = (const float*)d_in[6];
    const float* W2      = (const float*)d_in[7];
    const float* g2      = (const float*)d_in[8];
    const float* b2      = (const float*)d_in[9];

    char* ws = (char*)d_ws;
    int*   idxb = (int*)(ws + OFF_IDX);
    float* wb   = (float*)(ws + OFF_W);
    u16*   wt1b = (u16*)(ws + OFF_WT1B);
    u16*   wt2b = (u16*)(ws + OFF_WT2B);
    float* st1  = (float*)(ws + OFF_ST1);
    float* st2  = (float*)(ws + OFF_ST2);
    float* p1   = (float*)(ws + OFF_P1);
    float* p2   = (float*)(ws + OFF_P2);
    u16*   h1   = (u16*)(ws + OFF_H1);
    u16*   h2   = (u16*)(ws + OFF_H2);
    float* outp = (float*)d_out;

    prep_kernel<<<320, 256, 0, stream>>>(W1, W2, wt1b, wt2b);
    knn_kernel<<<1024, 256, 0, stream>>>(xyz1, xyz2, idxb, wb);
    gemm1_kernel<<<1024, 256, 0, stream>>>(points1, points2, idxb, wb, wt1b, h1, p1);
    reduce_kernel<<<16, 256, 0, stream>>>(p1, 1024, 256, 1.0f / 65536.0f, g1, b1, st1);
    gemm2_kernel<<<512, 256, 0, stream>>>(h1, wt2b, st1, h2, p2);
    reduce_kernel<<<8, 256, 0, stream>>>(p2, 512, 128, 1.0f / 65536.0f, g2, b2, st2);
    final_kernel<<<4096, 256, 0, stream>>>(h2, st2, outp);
}